// Round 1
// baseline (605.371 us; speedup 1.0000x reference)
//
#include <hip/hip_runtime.h>

#define NN 50000
#define NE 640000
#define DIM 128

// monotonic float<->uint encoding for atomicMax on floats
__device__ __forceinline__ unsigned ford(float f) {
    unsigned u = __float_as_uint(f);
    return (u & 0x80000000u) ? ~u : (u | 0x80000000u);
}
__device__ __forceinline__ float funord(unsigned u) {
    return (u & 0x80000000u) ? __uint_as_float(u ^ 0x80000000u)
                             : __uint_as_float(~u);
}

// wave-per-node: gate = x.w + b ; out[:,0:128] = x ; out[:,128:256] = 0 ; init scratch
__global__ void k_gate_init(const float* __restrict__ x,
                            const float* __restrict__ gw,
                            const float* __restrict__ gb,
                            float* __restrict__ out,
                            float* __restrict__ gate,
                            unsigned* __restrict__ segmax,
                            float* __restrict__ denom) {
    int wid = (blockIdx.x * blockDim.x + threadIdx.x) >> 6;
    int lane = threadIdx.x & 63;
    if (wid >= NN) return;
    const float2* xr = (const float2*)(x + (size_t)wid * DIM);
    const float2* wr = (const float2*)gw;
    float2 xv = xr[lane];
    float2 wv = wr[lane];
    float p = xv.x * wv.x + xv.y * wv.y;
    #pragma unroll
    for (int off = 32; off; off >>= 1) p += __shfl_xor(p, off);
    float2* o = (float2*)(out + (size_t)wid * (2 * DIM));
    o[lane] = xv;
    float2 z; z.x = 0.f; z.y = 0.f;
    o[64 + lane] = z;
    if (lane == 0) {
        gate[wid] = p + gb[0];
        segmax[wid] = 0u;           // sentinel: below any finite encoded float
        denom[wid] = 0.f;
    }
}

__global__ void k_segmax(const int* __restrict__ src, const int* __restrict__ dst,
                         const float* __restrict__ gate, unsigned* __restrict__ segmax) {
    int e = blockIdx.x * blockDim.x + threadIdx.x;
    if (e >= NE) return;
    float s = gate[src[e]];
    atomicMax(&segmax[dst[e]], ford(s));
}

__global__ void k_denom(const int* __restrict__ src, const int* __restrict__ dst,
                        const float* __restrict__ gate, const unsigned* __restrict__ segmax,
                        float* __restrict__ denom) {
    int e = blockIdx.x * blockDim.x + threadIdx.x;
    if (e >= NE) return;
    int d = dst[e];
    float m = funord(segmax[d]);
    float w = __expf(gate[src[e]] - m);
    atomicAdd(&denom[d], w);
}

// wave-per-edge: out[dst, 128+d] += alpha * x[src, d]
__global__ void k_agg(const int* __restrict__ src, const int* __restrict__ dst,
                      const float* __restrict__ gate, const unsigned* __restrict__ segmax,
                      const float* __restrict__ denom,
                      const float* __restrict__ x, float* __restrict__ out) {
    int wid = (blockIdx.x * blockDim.x + threadIdx.x) >> 6;
    int lane = threadIdx.x & 63;
    if (wid >= NE) return;
    int s = src[wid];
    int d = dst[wid];
    float m = funord(segmax[d]);
    float alpha = __expf(gate[s] - m) / fmaxf(denom[d], 1e-16f);
    const float2* xs = (const float2*)(x + (size_t)s * DIM);
    float2 v = xs[lane];
    float* o = out + (size_t)d * (2 * DIM) + DIM;
    atomicAdd(&o[2 * lane], alpha * v.x);
    atomicAdd(&o[2 * lane + 1], alpha * v.y);
}

extern "C" void kernel_launch(void* const* d_in, const int* in_sizes, int n_in,
                              void* d_out, int out_size, void* d_ws, size_t ws_size,
                              hipStream_t stream) {
    const float* x  = (const float*)d_in[0];
    const float* gw = (const float*)d_in[1];
    const float* gb = (const float*)d_in[2];
    const int* ei   = (const int*)d_in[3];
    const int* src  = ei;           // edge_index[0]
    const int* dst  = ei + NE;      // edge_index[1]
    float* out = (float*)d_out;

    float* gate      = (float*)d_ws;
    unsigned* segmax = (unsigned*)(gate + NN);
    float* denom     = (float*)(segmax + NN);

    // 1) gate + output init (wave per node, 4 nodes per 256-thread block)
    {
        int waves = NN;
        int blocks = (waves * 64 + 255) / 256;
        k_gate_init<<<blocks, 256, 0, stream>>>(x, gw, gb, out, gate, segmax, denom);
    }
    // 2) segment max over dst
    k_segmax<<<(NE + 255) / 256, 256, 0, stream>>>(src, dst, gate, segmax);
    // 3) denom
    k_denom<<<(NE + 255) / 256, 256, 0, stream>>>(src, dst, gate, segmax, denom);
    // 4) weighted scatter-sum (wave per edge)
    {
        int blocks = (NE * 64 + 255) / 256;
        k_agg<<<blocks, 256, 0, stream>>>(src, dst, gate, segmax, denom, x, out);
    }
}

// Round 2
// 132.401 us; speedup vs baseline: 4.5722x; 4.5722x over previous
//
#include <hip/hip_runtime.h>

#define NN 50000
#define NE 640000
#define DIM 128
#define NCHUNK 49   // ceil(NN/1024)

// ---------------- kernel 1: gate scores + out x-half + zero counts ----------------
__global__ void k_gate(const float* __restrict__ x,
                       const float* __restrict__ gw,
                       const float* __restrict__ gb,
                       float* __restrict__ out,
                       float* __restrict__ gate,
                       int* __restrict__ cnt) {
    int wid = (blockIdx.x * blockDim.x + threadIdx.x) >> 6;
    int lane = threadIdx.x & 63;
    if (wid >= NN) return;
    const float2* xr = (const float2*)(x + (size_t)wid * DIM);
    const float2* wr = (const float2*)gw;
    float2 xv = xr[lane];
    float2 wv = wr[lane];
    float p = xv.x * wv.x + xv.y * wv.y;
    #pragma unroll
    for (int off = 32; off; off >>= 1) p += __shfl_xor(p, off);
    float2* o = (float2*)(out + (size_t)wid * (2 * DIM));
    o[lane] = xv;
    if (lane == 0) {
        gate[wid] = p + gb[0];
        cnt[wid] = 0;
    }
}

// ---------------- kernel 2: degree histogram ----------------
__global__ void k_count(const int* __restrict__ dst, int* __restrict__ cnt) {
    int e = blockIdx.x * blockDim.x + threadIdx.x;
    if (e >= NE) return;
    atomicAdd(&cnt[dst[e]], 1);
}

// ---------------- scan (3 kernels) ----------------
__global__ void k_scan_a(const int* __restrict__ cnt, int* __restrict__ off,
                         int* __restrict__ bsum) {
    __shared__ int wsum[16];
    int tid = threadIdx.x;
    int i = blockIdx.x * 1024 + tid;
    int v = (i < NN) ? cnt[i] : 0;
    int incl = v;
    #pragma unroll
    for (int s = 1; s < 64; s <<= 1) {
        int t = __shfl_up(incl, s);
        if ((tid & 63) >= s) incl += t;
    }
    int wave = tid >> 6;
    if ((tid & 63) == 63) wsum[wave] = incl;
    __syncthreads();
    if (tid < 16) {
        int t = wsum[tid];
        #pragma unroll
        for (int s = 1; s < 16; s <<= 1) {
            int u = __shfl_up(t, s);
            if (tid >= s) t += u;
        }
        wsum[tid] = t;
    }
    __syncthreads();
    int waveoff = wave ? wsum[wave - 1] : 0;
    incl += waveoff;
    if (i < NN) off[i] = incl - v;   // chunk-local exclusive
    if (tid == 1023) bsum[blockIdx.x] = incl;
}

__global__ void k_scan_b(const int* __restrict__ bsum, int* __restrict__ boff) {
    int tid = threadIdx.x;  // 64
    int v = (tid < NCHUNK) ? bsum[tid] : 0;
    int incl = v;
    #pragma unroll
    for (int s = 1; s < 64; s <<= 1) {
        int t = __shfl_up(incl, s);
        if (tid >= s) incl += t;
    }
    if (tid < NCHUNK) boff[tid] = incl - v;
}

__global__ void k_scan_c(int* __restrict__ off, const int* __restrict__ boff,
                         int* __restrict__ cur) {
    int i = blockIdx.x * 1024 + threadIdx.x;
    if (i < NN) {
        int val = off[i] + boff[blockIdx.x];
        off[i] = val;
        cur[i] = val;
    }
    if (i == 0) off[NN] = NE;
}

// ---------------- kernel 4: scatter edges into CSR order ----------------
__global__ void k_scatter(const int* __restrict__ src, const int* __restrict__ dst,
                          const float* __restrict__ gate,
                          int* __restrict__ cur,
                          int* __restrict__ esrc, float* __restrict__ escore) {
    int e = blockIdx.x * blockDim.x + threadIdx.x;
    if (e >= NE) return;
    int s = src[e];
    int d = dst[e];
    int pos = atomicAdd(&cur[d], 1);
    esrc[pos] = s;
    escore[pos] = gate[s];
}

// ---------------- kernel 5: per-node softmax-weighted aggregation ----------------
__global__ void k_node_agg(const int* __restrict__ off,
                           const int* __restrict__ esrc,
                           const float* __restrict__ escore,
                           const float* __restrict__ x,
                           float* __restrict__ out) {
    int wid = (blockIdx.x * blockDim.x + threadIdx.x) >> 6;
    int lane = threadIdx.x & 63;
    if (wid >= NN) return;
    int b = off[wid];
    int e = off[wid + 1];

    // pass A: max and denom, edges distributed across lanes (coalesced escore reads)
    float m = -INFINITY;
    for (int j = b + lane; j < e; j += 64) m = fmaxf(m, escore[j]);
    #pragma unroll
    for (int o_ = 32; o_; o_ >>= 1) m = fmaxf(m, __shfl_xor(m, o_));
    float dsum = 0.f;
    for (int j = b + lane; j < e; j += 64) dsum += __expf(escore[j] - m);
    #pragma unroll
    for (int o_ = 32; o_; o_ >>= 1) dsum += __shfl_xor(dsum, o_);
    float inv = 1.0f / fmaxf(dsum, 1e-16f);

    // pass B: half-wave per edge, float4 loads (2 edges concurrently)
    int half = lane >> 5;   // 0 or 1
    int hl = lane & 31;     // 0..31, hl*4 floats = full 128 dims across 32 lanes
    float4 acc = make_float4(0.f, 0.f, 0.f, 0.f);
    #pragma unroll 2
    for (int j = b + half; j < e; j += 2) {
        int s = esrc[j];
        float w = __expf(escore[j] - m) * inv;
        const float4* xs = (const float4*)(x + (size_t)s * DIM);
        float4 v = xs[hl];
        acc.x += w * v.x;
        acc.y += w * v.y;
        acc.z += w * v.z;
        acc.w += w * v.w;
    }
    // combine the two halves (lane l and l+32 hold the same dims)
    acc.x += __shfl_xor(acc.x, 32);
    acc.y += __shfl_xor(acc.y, 32);
    acc.z += __shfl_xor(acc.z, 32);
    acc.w += __shfl_xor(acc.w, 32);
    float* o = out + (size_t)wid * (2 * DIM) + DIM;
    if (half == 0) ((float4*)o)[hl] = acc;
}

extern "C" void kernel_launch(void* const* d_in, const int* in_sizes, int n_in,
                              void* d_out, int out_size, void* d_ws, size_t ws_size,
                              hipStream_t stream) {
    const float* x  = (const float*)d_in[0];
    const float* gw = (const float*)d_in[1];
    const float* gb = (const float*)d_in[2];
    const int* ei   = (const int*)d_in[3];
    const int* src  = ei;           // edge_index[0]
    const int* dst  = ei + NE;      // edge_index[1]
    float* out = (float*)d_out;

    // workspace layout
    float* gate   = (float*)d_ws;            // NN
    int*   cnt    = (int*)(gate + NN);       // NN
    int*   off    = cnt + NN;                // NN+1
    int*   cur    = off + NN + 1;            // NN
    int*   bsum   = cur + NN;                // 64
    int*   boff   = bsum + 64;               // 64
    int*   esrc   = boff + 64;               // NE
    float* escore = (float*)(esrc + NE);     // NE

    k_gate<<<(NN * 64 + 255) / 256, 256, 0, stream>>>(x, gw, gb, out, gate, cnt);
    k_count<<<(NE + 255) / 256, 256, 0, stream>>>(dst, cnt);
    k_scan_a<<<NCHUNK, 1024, 0, stream>>>(cnt, off, bsum);
    k_scan_b<<<1, 64, 0, stream>>>(bsum, boff);
    k_scan_c<<<NCHUNK, 1024, 0, stream>>>(off, boff, cur);
    k_scatter<<<(NE + 255) / 256, 256, 0, stream>>>(src, dst, gate, cur, esrc, escore);
    k_node_agg<<<(NN * 64 + 255) / 256, 256, 0, stream>>>(off, esrc, escore, x, out);
}